// Round 1
// baseline (1498.390 us; speedup 1.0000x reference)
//
#include <hip/hip_runtime.h>
#include <hip/hip_bf16.h>

#define BATCH 64
#define EPS_BN 1e-5f

typedef __bf16 bf16_t;
typedef __bf16 bf16x8 __attribute__((ext_vector_type(8)));
typedef float floatx4 __attribute__((ext_vector_type(4)));

// ---------------- conv (3x3, stride 2, pad 1) + bias + relu ----------------
template<int CIN, int HOUT>
__global__ __launch_bounds__(256) void conv_relu_kernel(
    const float* __restrict__ in, const float* __restrict__ w,
    const float* __restrict__ bias, float* __restrict__ out, int total)
{
    int idx = blockIdx.x * 256 + threadIdx.x;
    if (idx >= total) return;
    const int HIN = 2 * HOUT;
    int ox = idx % HOUT;
    int tmp = idx / HOUT;
    int oy = tmp % HOUT; tmp /= HOUT;
    int co = tmp % 24;
    int b  = tmp / 24;
    float acc = bias[co];
    const float* wp = w + co * CIN * 9;
    const float* ip = in + b * CIN * HIN * HIN;
    int iy0 = 2 * oy - 1, ix0 = 2 * ox - 1;
    for (int ci = 0; ci < CIN; ci++) {
        #pragma unroll
        for (int ky = 0; ky < 3; ky++) {
            int iy = iy0 + ky;
            if ((unsigned)iy < (unsigned)HIN) {
                #pragma unroll
                for (int kx = 0; kx < 3; kx++) {
                    int ix = ix0 + kx;
                    if ((unsigned)ix < (unsigned)HIN)
                        acc = fmaf(ip[(ci * HIN + iy) * HIN + ix],
                                   wp[(ci * 3 + ky) * 3 + kx], acc);
                }
            }
        }
    }
    out[idx] = fmaxf(acc, 0.0f);
}

// ---------------- batchnorm stats (train-mode batch stats) -> scale/shift ----
__global__ __launch_bounds__(256) void bn_stats_kernel(
    const float* __restrict__ y, const float* __restrict__ g,
    const float* __restrict__ bbp, float* __restrict__ scale,
    float* __restrict__ shift, int HW)
{
    int c = blockIdx.x;  // 24 channels
    float s = 0.f, s2 = 0.f;
    for (int b = 0; b < BATCH; b++) {
        const float* p = y + (b * 24 + c) * HW;
        for (int i = threadIdx.x; i < HW; i += 256) {
            float v = p[i];
            s += v;
            s2 = fmaf(v, v, s2);
        }
    }
    __shared__ float rs[256], rs2[256];
    rs[threadIdx.x] = s; rs2[threadIdx.x] = s2;
    __syncthreads();
    for (int o = 128; o > 0; o >>= 1) {
        if (threadIdx.x < o) {
            rs[threadIdx.x]  += rs[threadIdx.x + o];
            rs2[threadIdx.x] += rs2[threadIdx.x + o];
        }
        __syncthreads();
    }
    if (threadIdx.x == 0) {
        float n = (float)(BATCH * HW);
        float m = rs[0] / n;
        float var = rs2[0] / n - m * m;
        float sc = g[c] * rsqrtf(var + EPS_BN);
        scale[c] = sc;
        shift[c] = fmaf(-m, sc, bbp[c]);
    }
}

// ---------------- apply batchnorm in place ----------------
__global__ __launch_bounds__(256) void bn_apply_kernel(
    float* __restrict__ y, const float* __restrict__ scale,
    const float* __restrict__ shift, int HW, int total)
{
    int idx = blockIdx.x * 256 + threadIdx.x;
    if (idx >= total) return;
    int c = (idx / HW) % 24;
    y[idx] = fmaf(y[idx], scale[c], shift[c]);
}

// ---------------- transpose gw2/3/4 to bf16 Wt[l][c][k] ----------------
__global__ __launch_bounds__(256) void prep_wt_kernel(
    const float* __restrict__ g2, const float* __restrict__ g3,
    const float* __restrict__ g4, bf16_t* __restrict__ wt)
{
    int l = blockIdx.x / 8;
    int kc = blockIdx.x % 8;
    const float* gw = (l == 0) ? g2 : ((l == 1) ? g3 : g4);
    int c = threadIdx.x;
    for (int k = kc * 32; k < kc * 32 + 32; k++)
        wt[(l * 256 + c) * 256 + k] = (bf16_t)gw[k * 256 + c];
}

// ---------------- wq[b][c] = q[b] @ gw1[52:63] + gb1 ----------------
__global__ __launch_bounds__(256) void wq_kernel(
    const float* __restrict__ q, const float* __restrict__ gw1,
    const float* __restrict__ gb1, float* __restrict__ wq)
{
    int b = blockIdx.x, c = threadIdx.x;
    float acc = gb1[c];
    #pragma unroll
    for (int d = 0; d < 11; d++)
        acc = fmaf(q[b * 11 + d], gw1[(52 + d) * 256 + c], acc);
    wq[b * 256 + c] = acc;
}

// ---------------- U[b,n] = o(b,n) @ gw1[0:26]; V = o @ gw1[26:52] -----------
// o = [bn4(x4 features 0..23), (n/8)/8, (n%8)/8]
__global__ __launch_bounds__(256) void uv_kernel(
    const float* __restrict__ x4, const float* __restrict__ sc4,
    const float* __restrict__ sh4, const float* __restrict__ gw1,
    float* __restrict__ U, float* __restrict__ V)
{
    int b = blockIdx.x >> 6, n = blockIdx.x & 63;
    __shared__ float o[26];
    int t = threadIdx.x;
    if (t < 24)       o[t]  = fmaf(x4[(b * 24 + t) * 64 + n], sc4[t], sh4[t]);
    else if (t == 24) o[24] = (float)(n >> 3) * 0.125f;
    else if (t == 25) o[25] = (float)(n & 7) * 0.125f;
    __syncthreads();
    float u = 0.f, v = 0.f;
    #pragma unroll
    for (int f = 0; f < 26; f++) {
        float of = o[f];
        u = fmaf(of, gw1[f * 256 + t], u);
        v = fmaf(of, gw1[(26 + f) * 256 + t], v);
    }
    U[blockIdx.x * 256 + t] = u;
    V[blockIdx.x * 256 + t] = v;
}

// ---------------- fused pair MLP: one block per (b, i) ----------------
// h1[j][c] = relu(U[b,i,c] + V[b,j,c] + wq[b,c]) -> 3x (MFMA 256x256 + relu)
// emits partial[bi][c] = sum_j h4[j][c]
__global__ __launch_bounds__(256, 3) void pair_kernel(
    const float* __restrict__ U, const float* __restrict__ V,
    const float* __restrict__ wq, const bf16_t* __restrict__ wt,
    const float* __restrict__ gb2, const float* __restrict__ gb3,
    const float* __restrict__ gb4, float* __restrict__ partial)
{
    __shared__ bf16_t hA[64][264];   // +8 pad: conflict-free MFMA A reads, 16B aligned rows
    int bi = blockIdx.x;
    int b  = bi >> 6;
    int t  = threadIdx.x;

    // ---- build h1 into LDS (bf16)
    {
        float uw = U[bi * 256 + t] + wq[b * 256 + t];
        const float* Vb = V + (b << 6) * 256;
        for (int j = 0; j < 64; j++) {
            float v = Vb[j * 256 + t];
            hA[j][t] = (bf16_t)fmaxf(uw + v, 0.0f);
        }
    }
    __syncthreads();

    int lane = t & 63, wave = t >> 6;
    int wm = wave >> 1, wn = wave & 1;         // wave tile: rows wm*32..+31, cols wn*128..+127
    int l15 = lane & 15, l4 = lane >> 4;
    int arow0 = wm * 32 + l15;
    int kofs  = l4 * 8;
    int bcol0 = wn * 128 + l15;

    const floatx4 zero4 = {0.f, 0.f, 0.f, 0.f};
    #pragma unroll 1
    for (int layer = 0; layer < 3; layer++) {
        const bf16_t* W = wt + layer * 256 * 256;   // Wt[c][k]
        const float* bias = (layer == 0) ? gb2 : ((layer == 1) ? gb3 : gb4);
        floatx4 acc[2][8];
        #pragma unroll
        for (int mt = 0; mt < 2; mt++)
            #pragma unroll
            for (int nt = 0; nt < 8; nt++) acc[mt][nt] = zero4;

        #pragma unroll
        for (int kt = 0; kt < 8; kt++) {
            int k = kt * 32 + kofs;
            bf16x8 a0 = *(const bf16x8*)&hA[arow0][k];
            bf16x8 a1 = *(const bf16x8*)&hA[arow0 + 16][k];
            bf16x8 bfr[8];
            #pragma unroll
            for (int nt = 0; nt < 8; nt++)
                bfr[nt] = *(const bf16x8*)&W[(bcol0 + nt * 16) * 256 + k];
            #pragma unroll
            for (int nt = 0; nt < 8; nt++) {
                acc[0][nt] = __builtin_amdgcn_mfma_f32_16x16x32_bf16(a0, bfr[nt], acc[0][nt], 0, 0, 0);
                acc[1][nt] = __builtin_amdgcn_mfma_f32_16x16x32_bf16(a1, bfr[nt], acc[1][nt], 0, 0, 0);
            }
        }
        __syncthreads();   // all reads of hA complete before overwrite
        #pragma unroll
        for (int mt = 0; mt < 2; mt++) {
            int row = wm * 32 + mt * 16 + l4 * 4;
            #pragma unroll
            for (int nt = 0; nt < 8; nt++) {
                int col = wn * 128 + nt * 16 + l15;
                float bc = bias[col];
                #pragma unroll
                for (int r = 0; r < 4; r++) {
                    float vv = fmaxf(acc[mt][nt][r] + bc, 0.0f);
                    hA[row + r][col] = (bf16_t)vv;
                }
            }
        }
        __syncthreads();   // writes visible before next layer reads
    }

    // ---- column sums over the 64 rows
    float s = 0.f;
    for (int j = 0; j < 64; j++) s += (float)hA[j][t];
    partial[bi * 256 + t] = s;
}

// ---------------- f_phi: reduce partials -> mean -> 3 small GEMMs ------------
__global__ __launch_bounds__(256) void fphi_kernel(
    const float* __restrict__ partial,
    const float* __restrict__ fw1, const float* __restrict__ fb1,
    const float* __restrict__ fw2, const float* __restrict__ fb2,
    const float* __restrict__ fw3, const float* __restrict__ fb3,
    float* __restrict__ out)
{
    int b = blockIdx.x, t = threadIdx.x;
    __shared__ float g[256], h1[256], h2[256];
    float s = 0.f;
    for (int i = 0; i < 64; i++) s += partial[(b * 64 + i) * 256 + t];
    g[t] = s * (1.0f / 4096.0f);
    __syncthreads();
    float a1 = fb1[t];
    for (int k = 0; k < 256; k++) a1 = fmaf(g[k], fw1[k * 256 + t], a1);
    h1[t] = fmaxf(a1, 0.0f);
    __syncthreads();
    float a2 = fb2[t];
    for (int k = 0; k < 256; k++) a2 = fmaf(h1[k], fw2[k * 256 + t], a2);
    h2[t] = fmaxf(a2, 0.0f);
    __syncthreads();
    if (t < 10) {
        float a3 = fb3[t];
        for (int k = 0; k < 256; k++) a3 = fmaf(h2[k], fw3[k * 10 + t], a3);
        out[b * 10 + t] = a3;
    }
}

extern "C" void kernel_launch(void* const* d_in, const int* in_sizes, int n_in,
                              void* d_out, int out_size, void* d_ws, size_t ws_size,
                              hipStream_t stream)
{
    (void)in_sizes; (void)n_in; (void)out_size; (void)ws_size;
    const float* img = (const float*)d_in[0];
    const float* q   = (const float*)d_in[1];
    const float* cw[4] = {(const float*)d_in[2],  (const float*)d_in[6],
                          (const float*)d_in[10], (const float*)d_in[14]};
    const float* cb[4] = {(const float*)d_in[3],  (const float*)d_in[7],
                          (const float*)d_in[11], (const float*)d_in[15]};
    const float* bg[4] = {(const float*)d_in[4],  (const float*)d_in[8],
                          (const float*)d_in[12], (const float*)d_in[16]};
    const float* bbv[4] = {(const float*)d_in[5],  (const float*)d_in[9],
                           (const float*)d_in[13], (const float*)d_in[17]};
    const float* gw1 = (const float*)d_in[18]; const float* gb1 = (const float*)d_in[19];
    const float* gw2 = (const float*)d_in[20]; const float* gb2 = (const float*)d_in[21];
    const float* gw3 = (const float*)d_in[22]; const float* gb3 = (const float*)d_in[23];
    const float* gw4 = (const float*)d_in[24]; const float* gb4 = (const float*)d_in[25];
    const float* fw1 = (const float*)d_in[26]; const float* fb1 = (const float*)d_in[27];
    const float* fw2 = (const float*)d_in[28]; const float* fb2 = (const float*)d_in[29];
    const float* fw3 = (const float*)d_in[30]; const float* fb3 = (const float*)d_in[31];

    float* ws  = (float*)d_ws;
    float* x1  = ws;                    // 64*24*64*64 = 6291456
    float* x2  = x1 + 6291456;          // 1572864
    float* x3  = x2 + 1572864;          // 393216
    float* x4  = x3 + 393216;           // 98304
    float* scsh = x4 + 98304;           // 192: sc1,sh1,sc2,sh2,sc3,sh3,sc4,sh4 (24 each)
    float* U   = scsh + 192;            // 1048576
    float* V   = U + 1048576;           // 1048576
    float* wqv = V + 1048576;           // 16384
    float* part = wqv + 16384;          // 1048576
    bf16_t* wt = (bf16_t*)(part + 1048576);  // 3*256*256 bf16

    conv_relu_kernel<3, 64><<<24576, 256, 0, stream>>>(img, cw[0], cb[0], x1, 6291456);
    bn_stats_kernel<<<24, 256, 0, stream>>>(x1, bg[0], bbv[0], scsh + 0, scsh + 24, 4096);
    bn_apply_kernel<<<24576, 256, 0, stream>>>(x1, scsh + 0, scsh + 24, 4096, 6291456);

    conv_relu_kernel<24, 32><<<6144, 256, 0, stream>>>(x1, cw[1], cb[1], x2, 1572864);
    bn_stats_kernel<<<24, 256, 0, stream>>>(x2, bg[1], bbv[1], scsh + 48, scsh + 72, 1024);
    bn_apply_kernel<<<6144, 256, 0, stream>>>(x2, scsh + 48, scsh + 72, 1024, 1572864);

    conv_relu_kernel<24, 16><<<1536, 256, 0, stream>>>(x2, cw[2], cb[2], x3, 393216);
    bn_stats_kernel<<<24, 256, 0, stream>>>(x3, bg[2], bbv[2], scsh + 96, scsh + 120, 256);
    bn_apply_kernel<<<1536, 256, 0, stream>>>(x3, scsh + 96, scsh + 120, 256, 393216);

    conv_relu_kernel<24, 8><<<384, 256, 0, stream>>>(x3, cw[3], cb[3], x4, 98304);
    bn_stats_kernel<<<24, 256, 0, stream>>>(x4, bg[3], bbv[3], scsh + 144, scsh + 168, 64);
    // layer-4 BN folded into uv_kernel (no apply pass)

    prep_wt_kernel<<<24, 256, 0, stream>>>(gw2, gw3, gw4, wt);
    wq_kernel<<<64, 256, 0, stream>>>(q, gw1, gb1, wqv);
    uv_kernel<<<4096, 256, 0, stream>>>(x4, scsh + 144, scsh + 168, gw1, U, V);
    pair_kernel<<<4096, 256, 0, stream>>>(U, V, wqv, wt, gb2, gb3, gb4, part);
    fphi_kernel<<<64, 256, 0, stream>>>(part, fw1, fb1, fw2, fb2, fw3, fb3, (float*)d_out);
}

// Round 2
// 828.667 us; speedup vs baseline: 1.8082x; 1.8082x over previous
//
#include <hip/hip_runtime.h>
#include <hip/hip_bf16.h>

#define EPS_BN 1e-5f
#define NI 4

typedef __bf16 bf16_t;
typedef __bf16 bf16x8 __attribute__((ext_vector_type(8)));
typedef float floatx16 __attribute__((ext_vector_type(16)));

// ---------------- zero the stats accumulators ----------------
__global__ __launch_bounds__(256) void zero_kernel(float* __restrict__ sums) {
    if (threadIdx.x < 192) sums[threadIdx.x] = 0.f;
}

// ---------------- conv1: img(64,3,128,128) -> x1(64,24,64,64), bias+relu ----
__global__ __launch_bounds__(256) void conv1_kernel(
    const float* __restrict__ img, const float* __restrict__ w,
    const float* __restrict__ bias, float* __restrict__ out)
{
    const int TH = 16;
    int b = blockIdx.x / 4, ty = blockIdx.x % 4;
    int oy0 = ty * TH;
    __shared__ float tin[3][2 * TH + 1][130];
    int t = threadIdx.x;
    const int total = 3 * (2 * TH + 1) * 130;
    int iy_base = 2 * oy0 - 1;
    for (int idx = t; idx < total; idx += 256) {
        int rx = idx % 130;
        int rem = idx / 130;
        int ry = rem % (2 * TH + 1);
        int ci = rem / (2 * TH + 1);
        int iy = iy_base + ry, ix = rx - 1;
        float v = 0.f;
        if ((unsigned)iy < 128u && (unsigned)ix < 128u)
            v = img[(b * 3 + ci) * 16384 + iy * 128 + ix];
        tin[ci][ry][rx] = v;
    }
    __syncthreads();
    int ox = t % 64;
    int oy_l0 = (t / 64) * 4;
    for (int p = 0; p < 4; p++) {
        int oyl = oy_l0 + p;
        float acc[24];
        #pragma unroll
        for (int co = 0; co < 24; co++) acc[co] = bias[co];
        #pragma unroll
        for (int ci = 0; ci < 3; ci++)
            #pragma unroll
            for (int ky = 0; ky < 3; ky++)
                #pragma unroll
                for (int kx = 0; kx < 3; kx++) {
                    float v = tin[ci][2 * oyl + ky][2 * ox + kx];
                    const float* wp = w + ci * 9 + ky * 3 + kx;  // uniform -> SGPR
                    #pragma unroll
                    for (int co = 0; co < 24; co++)
                        acc[co] = fmaf(v, wp[co * 27], acc[co]);
                }
        int oy = oy0 + oyl;
        #pragma unroll
        for (int co = 0; co < 24; co++)
            out[(b * 24 + co) * 4096 + oy * 64 + ox] = fmaxf(acc[co], 0.f);
    }
}

// ---------------- convN (CIN=24): BN-folded input, bias+relu output --------
template<int HOUT, int TH>
__global__ __launch_bounds__(256) void convN_kernel(
    const float* __restrict__ in, const float* __restrict__ sums, float prev_n,
    const float* __restrict__ gamma, const float* __restrict__ beta,
    const float* __restrict__ w, const float* __restrict__ bias,
    float* __restrict__ out)
{
    const int HIN = 2 * HOUT, NT = HOUT * TH, TILES = HOUT / TH;
    int b = blockIdx.x / TILES, ty = blockIdx.x % TILES;
    int oy0 = ty * TH;
    __shared__ float tin[24][2 * TH + 1][2 * HOUT + 2];
    __shared__ float scf[24], shf[24];
    int t = threadIdx.x;
    if (t < 24) {
        float m = sums[t * 2] / prev_n;
        float var = sums[t * 2 + 1] / prev_n - m * m;
        float sc = gamma[t] * rsqrtf(var + EPS_BN);
        scf[t] = sc;
        shf[t] = fmaf(-m, sc, beta[t]);
    }
    __syncthreads();
    const int total = 24 * (2 * TH + 1) * (2 * HOUT + 2);
    int iy_base = 2 * oy0 - 1;
    for (int idx = t; idx < total; idx += NT) {
        int rx = idx % (2 * HOUT + 2);
        int rem = idx / (2 * HOUT + 2);
        int ry = rem % (2 * TH + 1);
        int ci = rem / (2 * TH + 1);
        int iy = iy_base + ry, ix = rx - 1;
        float v = 0.f;
        if ((unsigned)iy < (unsigned)HIN && (unsigned)ix < (unsigned)HIN)
            v = fmaf(in[(b * 24 + ci) * HIN * HIN + iy * HIN + ix], scf[ci], shf[ci]);
        tin[ci][ry][rx] = v;
    }
    __syncthreads();
    int ox = t % HOUT, oyl = t / HOUT;
    float acc[24];
    #pragma unroll
    for (int co = 0; co < 24; co++) acc[co] = bias[co];
    for (int ci = 0; ci < 24; ci++)
        #pragma unroll
        for (int ky = 0; ky < 3; ky++)
            #pragma unroll
            for (int kx = 0; kx < 3; kx++) {
                float v = tin[ci][2 * oyl + ky][2 * ox + kx];
                const float* wp = w + ci * 9 + ky * 3 + kx;  // uniform -> SGPR
                #pragma unroll
                for (int co = 0; co < 24; co++)
                    acc[co] = fmaf(v, wp[co * 216], acc[co]);
            }
    int oy = oy0 + oyl;
    #pragma unroll
    for (int co = 0; co < 24; co++)
        out[(b * 24 + co) * HOUT * HOUT + oy * HOUT + ox] = fmaxf(acc[co], 0.f);
}

// ---------------- per-channel sum/sumsq with atomic accumulation ----------
__global__ __launch_bounds__(256) void stats_kernel(
    const float* __restrict__ y, float* __restrict__ sums, int HW, int NB)
{
    int c = blockIdx.x % 24;
    int s = blockIdx.x / 24;
    float s1 = 0.f, s2 = 0.f;
    for (int b = s * NB; b < s * NB + NB; b++) {
        const float* p = y + (b * 24 + c) * HW;
        for (int i = threadIdx.x; i < HW; i += 256) {
            float v = p[i];
            s1 += v;
            s2 = fmaf(v, v, s2);
        }
    }
    #pragma unroll
    for (int off = 1; off < 64; off <<= 1) {
        s1 += __shfl_xor(s1, off);
        s2 += __shfl_xor(s2, off);
    }
    __shared__ float r1[4], r2[4];
    if ((threadIdx.x & 63) == 0) {
        r1[threadIdx.x >> 6] = s1;
        r2[threadIdx.x >> 6] = s2;
    }
    __syncthreads();
    if (threadIdx.x == 0) {
        float a1 = r1[0] + r1[1] + r1[2] + r1[3];
        float a2 = r2[0] + r2[1] + r2[2] + r2[3];
        atomicAdd(&sums[c * 2], a1);
        atomicAdd(&sums[c * 2 + 1], a2);
    }
}

// ---------------- transpose gw2/3/4 to bf16 Wt[l][c][k] ----------------
__global__ __launch_bounds__(256) void prep_wt_kernel(
    const float* __restrict__ g2, const float* __restrict__ g3,
    const float* __restrict__ g4, bf16_t* __restrict__ wt)
{
    int l = blockIdx.x / 8;
    int kc = blockIdx.x % 8;
    const float* gw = (l == 0) ? g2 : ((l == 1) ? g3 : g4);
    int c = threadIdx.x;
    for (int k = kc * 32; k < kc * 32 + 32; k++)
        wt[(l * 256 + c) * 256 + k] = (bf16_t)gw[k * 256 + c];
}

// ---------------- wq[b][c] = q[b] @ gw1[52:63] + gb1 ----------------
__global__ __launch_bounds__(256) void wq_kernel(
    const float* __restrict__ q, const float* __restrict__ gw1,
    const float* __restrict__ gb1, float* __restrict__ wq)
{
    int b = blockIdx.x, c = threadIdx.x;
    float acc = gb1[c];
    #pragma unroll
    for (int d = 0; d < 11; d++)
        acc = fmaf(q[b * 11 + d], gw1[(52 + d) * 256 + c], acc);
    wq[b * 256 + c] = acc;
}

// ---------------- U/V with BN4 folded; o = [bn4(x4), coords] ---------------
__global__ __launch_bounds__(256) void uv_kernel(
    const float* __restrict__ x4, const float* __restrict__ sums4,
    const float* __restrict__ g4, const float* __restrict__ b4,
    const float* __restrict__ gw1, float* __restrict__ U, float* __restrict__ V)
{
    int b = blockIdx.x >> 2, n0 = (blockIdx.x & 3) * 16;
    __shared__ float o[16][26];
    int t = threadIdx.x;
    for (int idx = t; idx < 16 * 26; idx += 256) {
        int n = idx / 26, f = idx % 26;
        int ng = n0 + n;
        float val;
        if (f < 24) {
            float m = sums4[f * 2] * (1.f / 4096.f);
            float var = sums4[f * 2 + 1] * (1.f / 4096.f) - m * m;
            float sc = g4[f] * rsqrtf(var + EPS_BN);
            float sh = fmaf(-m, sc, b4[f]);
            val = fmaf(x4[(b * 24 + f) * 64 + ng], sc, sh);
        } else if (f == 24) val = (float)(ng >> 3) * 0.125f;
        else                val = (float)(ng & 7) * 0.125f;
        o[n][f] = val;
    }
    __syncthreads();
    float g1u[26], g1v[26];
    #pragma unroll
    for (int f = 0; f < 26; f++) {
        g1u[f] = gw1[f * 256 + t];
        g1v[f] = gw1[(26 + f) * 256 + t];
    }
    for (int n = 0; n < 16; n++) {
        float u = 0.f, v = 0.f;
        #pragma unroll
        for (int f = 0; f < 26; f++) {
            float of = o[n][f];
            u = fmaf(of, g1u[f], u);
            v = fmaf(of, g1v[f], v);
        }
        int ng = n0 + n;
        U[(b * 64 + ng) * 256 + t] = u;
        V[(b * 64 + ng) * 256 + t] = v;
    }
}

// ---------------- fused pair MLP: NI=4 i's per block ----------------
// waves: wm=rows-half (32), wn=cols-half (128). B-frags hoisted to VGPRs per
// layer (reused across 4 i's); A from LDS; layer-3 output reduced in regs.
__global__ __launch_bounds__(256, 1) void pair_kernel(
    const float* __restrict__ U, const float* __restrict__ V,
    const float* __restrict__ wq, const bf16_t* __restrict__ wt,
    const float* __restrict__ gb2, const float* __restrict__ gb3,
    const float* __restrict__ gb4, float* __restrict__ partial)
{
    __shared__ __align__(16) bf16_t hA[NI][64][264];
    __shared__ float csum[256];
    int blk = blockIdx.x;
    int b = blk >> 4;
    int i0 = (blk & 15) * NI;
    int t = threadIdx.x;

    // ---- build h1 for all NI i's: V read once per block
    {
        float wqv = wq[b * 256 + t];
        float uw[NI];
        #pragma unroll
        for (int ii = 0; ii < NI; ii++)
            uw[ii] = U[(b * 64 + i0 + ii) * 256 + t] + wqv;
        const float* Vb = V + (b * 64) * 256;
        for (int j = 0; j < 64; j++) {
            float v = Vb[j * 256 + t];
            #pragma unroll
            for (int ii = 0; ii < NI; ii++)
                hA[ii][j][t] = (bf16_t)fmaxf(uw[ii] + v, 0.0f);
        }
    }
    __syncthreads();

    int lane = t & 63, wave = t >> 6;
    int wm = wave >> 1, wn = wave & 1;
    int l31 = lane & 31, l2 = lane >> 5;
    int arow = wm * 32 + l31;
    const floatx16 zero16 = {0.f, 0.f, 0.f, 0.f, 0.f, 0.f, 0.f, 0.f,
                             0.f, 0.f, 0.f, 0.f, 0.f, 0.f, 0.f, 0.f};
    float colsum[4] = {0.f, 0.f, 0.f, 0.f};

    #pragma unroll 1
    for (int layer = 0; layer < 3; layer++) {
        const bf16_t* W = wt + layer * 65536;
        const float* bias = (layer == 0) ? gb2 : ((layer == 1) ? gb3 : gb4);
        // hoist B fragments: 4 nt x 16 kt, 8 bf16 each (256 VGPRs)
        bf16x8 Bf[4][16];
        #pragma unroll
        for (int nt = 0; nt < 4; nt++) {
            const bf16_t* Wc = W + (wn * 128 + nt * 32 + l31) * 256 + l2 * 8;
            #pragma unroll
            for (int kt = 0; kt < 16; kt++)
                Bf[nt][kt] = *(const bf16x8*)(Wc + kt * 16);
        }
        float bcol[4];
        #pragma unroll
        for (int nt = 0; nt < 4; nt++)
            bcol[nt] = bias[wn * 128 + nt * 32 + l31];

        #pragma unroll 1
        for (int ii = 0; ii < NI; ii++) {
            floatx16 acc[4];
            #pragma unroll
            for (int nt = 0; nt < 4; nt++) acc[nt] = zero16;
            #pragma unroll
            for (int kt = 0; kt < 16; kt++) {
                bf16x8 a = *(const bf16x8*)&hA[ii][arow][kt * 16 + l2 * 8];
                #pragma unroll
                for (int nt = 0; nt < 4; nt++)
                    acc[nt] = __builtin_amdgcn_mfma_f32_32x32x16_bf16(
                        a, Bf[nt][kt], acc[nt], 0, 0, 0);
            }
            if (layer < 2) {
                __syncthreads();  // all waves done reading hA[ii]
                #pragma unroll
                for (int nt = 0; nt < 4; nt++) {
                    int col = wn * 128 + nt * 32 + l31;
                    #pragma unroll
                    for (int reg = 0; reg < 16; reg++) {
                        int row = wm * 32 + (reg & 3) + 8 * (reg >> 2) + 4 * l2;
                        hA[ii][row][col] = (bf16_t)fmaxf(acc[nt][reg] + bcol[nt], 0.0f);
                    }
                }
                __syncthreads();  // writes visible before next use
            } else {
                #pragma unroll
                for (int nt = 0; nt < 4; nt++) {
                    float s = 0.f;
                    #pragma unroll
                    for (int reg = 0; reg < 16; reg++)
                        s += fmaxf(acc[nt][reg] + bcol[nt], 0.0f);
                    colsum[nt] += s;
                }
            }
        }
    }
    // reduce colsum: over l2 via shuffle, over wm via LDS
    #pragma unroll
    for (int nt = 0; nt < 4; nt++)
        colsum[nt] += __shfl_xor(colsum[nt], 32);
    __syncthreads();
    if (wm == 0 && l2 == 0) {
        #pragma unroll
        for (int nt = 0; nt < 4; nt++)
            csum[wn * 128 + nt * 32 + l31] = colsum[nt];
    }
    __syncthreads();
    if (wm == 1 && l2 == 0) {
        #pragma unroll
        for (int nt = 0; nt < 4; nt++) {
            int c = wn * 128 + nt * 32 + l31;
            partial[blk * 256 + c] = csum[c] + colsum[nt];
        }
    }
}

// ---------------- f_phi ----------------
__global__ __launch_bounds__(256) void fphi_kernel(
    const float* __restrict__ partial,
    const float* __restrict__ fw1, const float* __restrict__ fb1,
    const float* __restrict__ fw2, const float* __restrict__ fb2,
    const float* __restrict__ fw3, const float* __restrict__ fb3,
    float* __restrict__ out)
{
    int b = blockIdx.x, t = threadIdx.x;
    __shared__ float g[256], h1[256], h2[256];
    float s = 0.f;
    for (int k = 0; k < 16; k++) s += partial[(b * 16 + k) * 256 + t];
    g[t] = s * (1.0f / 4096.0f);
    __syncthreads();
    float a1 = fb1[t];
    for (int k = 0; k < 256; k++) a1 = fmaf(g[k], fw1[k * 256 + t], a1);
    h1[t] = fmaxf(a1, 0.0f);
    __syncthreads();
    float a2 = fb2[t];
    for (int k = 0; k < 256; k++) a2 = fmaf(h1[k], fw2[k * 256 + t], a2);
    h2[t] = fmaxf(a2, 0.0f);
    __syncthreads();
    if (t < 10) {
        float a3 = fb3[t];
        for (int k = 0; k < 256; k++) a3 = fmaf(h2[k], fw3[k * 10 + t], a3);
        out[b * 10 + t] = a3;
    }
}

extern "C" void kernel_launch(void* const* d_in, const int* in_sizes, int n_in,
                              void* d_out, int out_size, void* d_ws, size_t ws_size,
                              hipStream_t stream)
{
    (void)in_sizes; (void)n_in; (void)out_size; (void)ws_size;
    const float* img = (const float*)d_in[0];
    const float* q   = (const float*)d_in[1];
    const float* cw[4] = {(const float*)d_in[2],  (const float*)d_in[6],
                          (const float*)d_in[10], (const float*)d_in[14]};
    const float* cb[4] = {(const float*)d_in[3],  (const float*)d_in[7],
                          (const float*)d_in[11], (const float*)d_in[15]};
    const float* bg[4] = {(const float*)d_in[4],  (const float*)d_in[8],
                          (const float*)d_in[12], (const float*)d_in[16]};
    const float* bbv[4] = {(const float*)d_in[5],  (const float*)d_in[9],
                           (const float*)d_in[13], (const float*)d_in[17]};
    const float* gw1 = (const float*)d_in[18]; const float* gb1 = (const float*)d_in[19];
    const float* gw2 = (const float*)d_in[20]; const float* gb2 = (const float*)d_in[21];
    const float* gw3 = (const float*)d_in[22]; const float* gb3 = (const float*)d_in[23];
    const float* gw4 = (const float*)d_in[24]; const float* gb4 = (const float*)d_in[25];
    const float* fw1 = (const float*)d_in[26]; const float* fb1 = (const float*)d_in[27];
    const float* fw2 = (const float*)d_in[28]; const float* fb2 = (const float*)d_in[29];
    const float* fw3 = (const float*)d_in[30]; const float* fb3 = (const float*)d_in[31];

    float* ws  = (float*)d_ws;
    float* x1  = ws;                     // 6291456
    float* x2  = x1 + 6291456;           // 1572864
    float* x3  = x2 + 1572864;           // 393216
    float* x4  = x3 + 393216;            // 98304
    float* sums = x4 + 98304;            // 192  (4 layers x 24ch x {sum,sumsq})
    float* U   = sums + 192;             // 1048576
    float* V   = U + 1048576;            // 1048576
    float* wqv = V + 1048576;            // 16384
    float* part = wqv + 16384;           // 262144
    bf16_t* wt = (bf16_t*)(part + 262144);  // 3*256*256 bf16

    zero_kernel<<<1, 256, 0, stream>>>(sums);

    conv1_kernel<<<256, 256, 0, stream>>>(img, cw[0], cb[0], x1);
    stats_kernel<<<384, 256, 0, stream>>>(x1, sums + 0, 4096, 4);

    convN_kernel<32, 8><<<256, 256, 0, stream>>>(x1, sums + 0, 262144.f,
                                                 bg[0], bbv[0], cw[1], cb[1], x2);
    stats_kernel<<<96, 256, 0, stream>>>(x2, sums + 48, 1024, 16);

    convN_kernel<16, 8><<<128, 128, 0, stream>>>(x2, sums + 48, 65536.f,
                                                 bg[1], bbv[1], cw[2], cb[2], x3);
    stats_kernel<<<96, 256, 0, stream>>>(x3, sums + 96, 256, 16);

    convN_kernel<8, 8><<<64, 64, 0, stream>>>(x3, sums + 96, 16384.f,
                                              bg[2], bbv[2], cw[3], cb[3], x4);
    stats_kernel<<<24, 256, 0, stream>>>(x4, sums + 144, 64, 64);

    prep_wt_kernel<<<24, 256, 0, stream>>>(gw2, gw3, gw4, wt);
    wq_kernel<<<64, 256, 0, stream>>>(q, gw1, gb1, wqv);
    uv_kernel<<<256, 256, 0, stream>>>(x4, sums + 144, bg[3], bbv[3], gw1, U, V);

    pair_kernel<<<1024, 256, 0, stream>>>(U, V, wqv, wt, gb2, gb3, gb4, part);
    fphi_kernel<<<64, 256, 0, stream>>>(part, fw1, fb1, fw2, fb2, fw3, fb3,
                                        (float*)d_out);
}

// Round 3
// 705.662 us; speedup vs baseline: 2.1234x; 1.1743x over previous
//
#include <hip/hip_runtime.h>
#include <hip/hip_bf16.h>

#define EPS_BN 1e-5f

typedef __bf16 bf16_t;
typedef __bf16 bf16x8 __attribute__((ext_vector_type(8)));
typedef float floatx16 __attribute__((ext_vector_type(16)));

// ---------------- prep: zero stats + wq + pack W fragments ----------------
// wpack layout: ((((layer*2+wn)*4+nt)*16+kt)*64+lane)*8+e
//   lane = (k>>3 & 1)*32 + (col&31); col = wn*128+nt*32+(lane&31); k = kt*16+(lane>>5)*8+e
__global__ __launch_bounds__(256) void prep_kernel(
    const float* __restrict__ q, const float* __restrict__ gw1,
    const float* __restrict__ gb1, const float* __restrict__ g2,
    const float* __restrict__ g3, const float* __restrict__ g4,
    float* __restrict__ sums, float* __restrict__ wq, bf16_t* __restrict__ wpack)
{
    int blk = blockIdx.x, t = threadIdx.x;
    if (blk == 0 && t < 192) sums[t] = 0.f;
    // wq
    {
        float acc = gb1[t];
        #pragma unroll
        for (int d = 0; d < 11; d++)
            acc = fmaf(q[blk * 11 + d], gw1[(52 + d) * 256 + t], acc);
        wq[blk * 256 + t] = acc;
    }
    // pack W: 3*65536 elements over 64 blocks
    for (int idx = blk * 3072 + t; idx < blk * 3072 + 3072; idx += 256) {
        int layer = idx >> 16;
        int rem = idx & 65535;
        int col = rem & 255;
        int k = rem >> 8;
        const float* gw = (layer == 0) ? g2 : ((layer == 1) ? g3 : g4);
        float v = gw[k * 256 + col];
        int wn = col >> 7, nt = (col >> 5) & 3, l31 = col & 31;
        int kt = k >> 4, l2 = (k >> 3) & 1, e = k & 7;
        int lane = l2 * 32 + l31;
        wpack[((((layer * 2 + wn) * 4 + nt) * 16 + kt) * 64 + lane) * 8 + e] = (bf16_t)v;
    }
}

// ---------------- shared: block stats reduce (s1/s2[24] per thread) --------
template<int NW>
__device__ inline void stats_reduce(const float* s1, const float* s2,
                                    float* lds, float* sums)
{
    int t = threadIdx.x, lane = t & 63, w = t >> 6;
    #pragma unroll
    for (int co = 0; co < 24; co++) {
        float a = s1[co], bb = s2[co];
        #pragma unroll
        for (int off = 32; off > 0; off >>= 1) {
            a += __shfl_xor(a, off);
            bb += __shfl_xor(bb, off);
        }
        if (lane == 0) { lds[w * 48 + co * 2] = a; lds[w * 48 + co * 2 + 1] = bb; }
    }
    __syncthreads();
    if (t < 48) {
        float v = 0.f;
        #pragma unroll
        for (int w2 = 0; w2 < NW; w2++) v += lds[w2 * 48 + t];
        atomicAdd(&sums[t], v);
    }
}

// ---------------- conv1 + fused stats ----------------
__global__ __launch_bounds__(256) void conv1_kernel(
    const float* __restrict__ img, const float* __restrict__ w,
    const float* __restrict__ bias, float* __restrict__ out,
    float* __restrict__ sums)
{
    const int TH = 16;
    int b = blockIdx.x / 4, ty = blockIdx.x % 4;
    int oy0 = ty * TH;
    __shared__ float tin[3][2 * TH + 1][130];
    int t = threadIdx.x;
    const int total = 3 * (2 * TH + 1) * 130;
    int iy_base = 2 * oy0 - 1;
    for (int idx = t; idx < total; idx += 256) {
        int rx = idx % 130;
        int rem = idx / 130;
        int ry = rem % (2 * TH + 1);
        int ci = rem / (2 * TH + 1);
        int iy = iy_base + ry, ix = rx - 1;
        float v = 0.f;
        if ((unsigned)iy < 128u && (unsigned)ix < 128u)
            v = img[(b * 3 + ci) * 16384 + iy * 128 + ix];
        tin[ci][ry][rx] = v;
    }
    __syncthreads();
    int ox = t % 64;
    int oy_l0 = (t / 64) * 4;
    float s1[24], s2[24];
    #pragma unroll
    for (int co = 0; co < 24; co++) { s1[co] = 0.f; s2[co] = 0.f; }
    for (int p = 0; p < 4; p++) {
        int oyl = oy_l0 + p;
        float acc[24];
        #pragma unroll
        for (int co = 0; co < 24; co++) acc[co] = bias[co];
        #pragma unroll
        for (int ci = 0; ci < 3; ci++)
            #pragma unroll
            for (int ky = 0; ky < 3; ky++)
                #pragma unroll
                for (int kx = 0; kx < 3; kx++) {
                    float v = tin[ci][2 * oyl + ky][2 * ox + kx];
                    const float* wp = w + ci * 9 + ky * 3 + kx;  // uniform -> SGPR
                    #pragma unroll
                    for (int co = 0; co < 24; co++)
                        acc[co] = fmaf(v, wp[co * 27], acc[co]);
                }
        int oy = oy0 + oyl;
        #pragma unroll
        for (int co = 0; co < 24; co++) {
            float v = fmaxf(acc[co], 0.f);
            out[(b * 24 + co) * 4096 + oy * 64 + ox] = v;
            s1[co] += v;
            s2[co] = fmaf(v, v, s2[co]);
        }
    }
    __syncthreads();
    stats_reduce<4>(s1, s2, (float*)tin, sums);
}

// ---------------- convN + fused stats ----------------
template<int HOUT, int TH, int NW>
__global__ __launch_bounds__(256) void convN_kernel(
    const float* __restrict__ in, const float* __restrict__ sums_in, float prev_n,
    const float* __restrict__ gamma, const float* __restrict__ beta,
    const float* __restrict__ w, const float* __restrict__ bias,
    float* __restrict__ out, float* __restrict__ sums_out)
{
    const int HIN = 2 * HOUT, NT = HOUT * TH, TILES = HOUT / TH;
    int b = blockIdx.x / TILES, ty = blockIdx.x % TILES;
    int oy0 = ty * TH;
    __shared__ float tin[24][2 * TH + 1][2 * HOUT + 2];
    __shared__ float scf[24], shf[24];
    int t = threadIdx.x;
    if (t < 24) {
        float m = sums_in[t * 2] / prev_n;
        float var = sums_in[t * 2 + 1] / prev_n - m * m;
        float sc = gamma[t] * rsqrtf(var + EPS_BN);
        scf[t] = sc;
        shf[t] = fmaf(-m, sc, beta[t]);
    }
    __syncthreads();
    const int total = 24 * (2 * TH + 1) * (2 * HOUT + 2);
    int iy_base = 2 * oy0 - 1;
    for (int idx = t; idx < total; idx += NT) {
        int rx = idx % (2 * HOUT + 2);
        int rem = idx / (2 * HOUT + 2);
        int ry = rem % (2 * TH + 1);
        int ci = rem / (2 * TH + 1);
        int iy = iy_base + ry, ix = rx - 1;
        float v = 0.f;
        if ((unsigned)iy < (unsigned)HIN && (unsigned)ix < (unsigned)HIN)
            v = fmaf(in[(b * 24 + ci) * HIN * HIN + iy * HIN + ix], scf[ci], shf[ci]);
        tin[ci][ry][rx] = v;
    }
    __syncthreads();
    int ox = t % HOUT, oyl = t / HOUT;
    float acc[24];
    #pragma unroll
    for (int co = 0; co < 24; co++) acc[co] = bias[co];
    for (int ci = 0; ci < 24; ci++)
        #pragma unroll
        for (int ky = 0; ky < 3; ky++)
            #pragma unroll
            for (int kx = 0; kx < 3; kx++) {
                float v = tin[ci][2 * oyl + ky][2 * ox + kx];
                const float* wp = w + ci * 9 + ky * 3 + kx;  // uniform -> SGPR
                #pragma unroll
                for (int co = 0; co < 24; co++)
                    acc[co] = fmaf(v, wp[co * 216], acc[co]);
            }
    int oy = oy0 + oyl;
    float s1[24], s2[24];
    #pragma unroll
    for (int co = 0; co < 24; co++) {
        float v = fmaxf(acc[co], 0.f);
        out[(b * 24 + co) * HOUT * HOUT + oy * HOUT + ox] = v;
        s1[co] = v;
        s2[co] = v * v;
    }
    __syncthreads();
    stats_reduce<NW>(s1, s2, (float*)tin, sums_out);
}

// ---------------- U/V with BN4 folded ----------------
__global__ __launch_bounds__(256) void uv_kernel(
    const float* __restrict__ x4, const float* __restrict__ sums4,
    const float* __restrict__ g4, const float* __restrict__ b4,
    const float* __restrict__ gw1, float* __restrict__ U, float* __restrict__ V)
{
    int b = blockIdx.x >> 2, n0 = (blockIdx.x & 3) * 16;
    __shared__ float o[16][26];
    int t = threadIdx.x;
    for (int idx = t; idx < 16 * 26; idx += 256) {
        int n = idx / 26, f = idx % 26;
        int ng = n0 + n;
        float val;
        if (f < 24) {
            float m = sums4[f * 2] * (1.f / 4096.f);
            float var = sums4[f * 2 + 1] * (1.f / 4096.f) - m * m;
            float sc = g4[f] * rsqrtf(var + EPS_BN);
            float sh = fmaf(-m, sc, b4[f]);
            val = fmaf(x4[(b * 24 + f) * 64 + ng], sc, sh);
        } else if (f == 24) val = (float)(ng >> 3) * 0.125f;
        else                val = (float)(ng & 7) * 0.125f;
        o[n][f] = val;
    }
    __syncthreads();
    float g1u[26], g1v[26];
    #pragma unroll
    for (int f = 0; f < 26; f++) {
        g1u[f] = gw1[f * 256 + t];
        g1v[f] = gw1[(26 + f) * 256 + t];
    }
    for (int n = 0; n < 16; n++) {
        float u = 0.f, v = 0.f;
        #pragma unroll
        for (int f = 0; f < 26; f++) {
            float of = o[n][f];
            u = fmaf(of, g1u[f], u);
            v = fmaf(of, g1v[f], v);
        }
        int ng = n0 + n;
        U[(b * 64 + ng) * 256 + t] = u;
        V[(b * 64 + ng) * 256 + t] = v;
    }
}

// ---------------- fused pair MLP: 512 threads, 256 rows (4 i's) per block ---
// wave (wm 0..3, wn 0..1): rows wm*64..+63, cols wn*128..+127.
// B from packed W in L2, chunked 64-VGPR; acc 128 AGPR; 2 waves/SIMD.
__global__ __launch_bounds__(512, 2) void pair_kernel(
    const float* __restrict__ U, const float* __restrict__ V,
    const float* __restrict__ wq, const bf16_t* __restrict__ wpack,
    const float* __restrict__ gb2, const float* __restrict__ gb3,
    const float* __restrict__ gb4, float* __restrict__ partial)
{
    __shared__ __align__(16) bf16_t hA[256][264];
    __shared__ float csum[4][256];
    int blk = blockIdx.x;
    int b = blk >> 4;
    int i0 = (blk & 15) * 4;
    int t = threadIdx.x;

    // ---- build h1: 256 rows (4 i x 64 j) x 256 cols
    {
        int c = t & 255, jh = t >> 8;  // jh in 0..1
        float wqc = wq[b * 256 + c];
        float uw[4];
        #pragma unroll
        for (int ii = 0; ii < 4; ii++)
            uw[ii] = U[(b * 64 + i0 + ii) * 256 + c] + wqc;
        const float* Vb = V + (b * 64) * 256;
        for (int j = jh * 32; j < jh * 32 + 32; j++) {
            float v = Vb[j * 256 + c];
            #pragma unroll
            for (int ii = 0; ii < 4; ii++)
                hA[ii * 64 + j][c] = (bf16_t)fmaxf(uw[ii] + v, 0.0f);
        }
    }
    __syncthreads();

    int lane = t & 63, wave = t >> 6;
    int wm = wave >> 1, wn = wave & 1;
    int l31 = lane & 31, l2 = lane >> 5;
    int r0 = wm * 64 + l31;
    const floatx16 zero16 = {0.f, 0.f, 0.f, 0.f, 0.f, 0.f, 0.f, 0.f,
                             0.f, 0.f, 0.f, 0.f, 0.f, 0.f, 0.f, 0.f};
    float colsum[4] = {0.f, 0.f, 0.f, 0.f};

    #pragma unroll 1
    for (int layer = 0; layer < 3; layer++) {
        const float* bias = (layer == 0) ? gb2 : ((layer == 1) ? gb3 : gb4);
        const bf16_t* Wb = wpack + (size_t)((layer * 2 + wn) * 4) * 16 * 64 * 8;
        float bcol[4];
        #pragma unroll
        for (int nt = 0; nt < 4; nt++)
            bcol[nt] = bias[wn * 128 + nt * 32 + l31];

        floatx16 acc[2][4];
        #pragma unroll
        for (int mt = 0; mt < 2; mt++)
            #pragma unroll
            for (int nt = 0; nt < 4; nt++) acc[mt][nt] = zero16;

        #pragma unroll 1
        for (int kc = 0; kc < 4; kc++) {
            bf16x8 Bf[4][4];
            #pragma unroll
            for (int nt = 0; nt < 4; nt++)
                #pragma unroll
                for (int kk = 0; kk < 4; kk++)
                    Bf[nt][kk] = *(const bf16x8*)(Wb + ((nt * 16 + kc * 4 + kk) * 64 + lane) * 8);
            #pragma unroll
            for (int kk = 0; kk < 4; kk++) {
                int k = (kc * 4 + kk) * 16 + l2 * 8;
                bf16x8 a0 = *(const bf16x8*)&hA[r0][k];
                bf16x8 a1 = *(const bf16x8*)&hA[r0 + 32][k];
                #pragma unroll
                for (int nt = 0; nt < 4; nt++) {
                    acc[0][nt] = __builtin_amdgcn_mfma_f32_32x32x16_bf16(a0, Bf[nt][kk], acc[0][nt], 0, 0, 0);
                    acc[1][nt] = __builtin_amdgcn_mfma_f32_32x32x16_bf16(a1, Bf[nt][kk], acc[1][nt], 0, 0, 0);
                }
            }
        }

        if (layer < 2) {
            __syncthreads();  // all waves done reading hA
            #pragma unroll
            for (int mt = 0; mt < 2; mt++)
                #pragma unroll
                for (int nt = 0; nt < 4; nt++) {
                    int col = wn * 128 + nt * 32 + l31;
                    #pragma unroll
                    for (int reg = 0; reg < 16; reg++) {
                        int row = wm * 64 + mt * 32 + (reg & 3) + 8 * (reg >> 2) + 4 * l2;
                        hA[row][col] = (bf16_t)fmaxf(acc[mt][nt][reg] + bcol[nt], 0.0f);
                    }
                }
            __syncthreads();  // writes visible before next layer
        } else {
            #pragma unroll
            for (int nt = 0; nt < 4; nt++) {
                float s = 0.f;
                #pragma unroll
                for (int mt = 0; mt < 2; mt++)
                    #pragma unroll
                    for (int reg = 0; reg < 16; reg++)
                        s += fmaxf(acc[mt][nt][reg] + bcol[nt], 0.0f);
                colsum[nt] += s;
            }
        }
    }

    // reduce: xor-32 combines l2 halves; LDS combines wm
    #pragma unroll
    for (int nt = 0; nt < 4; nt++)
        colsum[nt] += __shfl_xor(colsum[nt], 32);
    if (l2 == 0) {
        #pragma unroll
        for (int nt = 0; nt < 4; nt++)
            csum[wm][wn * 128 + nt * 32 + l31] = colsum[nt];
    }
    __syncthreads();
    if (t < 256)
        partial[blk * 256 + t] = csum[0][t] + csum[1][t] + csum[2][t] + csum[3][t];
}

// ---------------- f_phi ----------------
__global__ __launch_bounds__(256) void fphi_kernel(
    const float* __restrict__ partial,
    const float* __restrict__ fw1, const float* __restrict__ fb1,
    const float* __restrict__ fw2, const float* __restrict__ fb2,
    const float* __restrict__ fw3, const float* __restrict__ fb3,
    float* __restrict__ out)
{
    int b = blockIdx.x, t = threadIdx.x;
    __shared__ float g[256], h1[256], h2[256];
    float s = 0.f;
    for (int k = 0; k < 16; k++) s += partial[(b * 16 + k) * 256 + t];
    g[t] = s * (1.0f / 4096.0f);
    __syncthreads();
    float a1 = fb1[t];
    for (int k = 0; k < 256; k++) a1 = fmaf(g[k], fw1[k * 256 + t], a1);
    h1[t] = fmaxf(a1, 0.0f);
    __syncthreads();
    float a2 = fb2[t];
    for (int k = 0; k < 256; k++) a2 = fmaf(h1[k], fw2[k * 256 + t], a2);
    h2[t] = fmaxf(a2, 0.0f);
    __syncthreads();
    if (t < 10) {
        float a3 = fb3[t];
        for (int k = 0; k < 256; k++) a3 = fmaf(h2[k], fw3[k * 10 + t], a3);
        out[b * 10 + t] = a3;
    }
}

extern "C" void kernel_launch(void* const* d_in, const int* in_sizes, int n_in,
                              void* d_out, int out_size, void* d_ws, size_t ws_size,
                              hipStream_t stream)
{
    (void)in_sizes; (void)n_in; (void)out_size; (void)ws_size;
    const float* img = (const float*)d_in[0];
    const float* q   = (const float*)d_in[1];
    const float* cw[4] = {(const float*)d_in[2],  (const float*)d_in[6],
                          (const float*)d_in[10], (const float*)d_in[14]};
    const float* cb[4] = {(const float*)d_in[3],  (const float*)d_in[7],
                          (const float*)d_in[11], (const float*)d_in[15]};
    const float* bg[4] = {(const float*)d_in[4],  (const float*)d_in[8],
                          (const float*)d_in[12], (const float*)d_in[16]};
    const float* bbv[4] = {(const float*)d_in[5],  (const float*)d_in[9],
                           (const float*)d_in[13], (const float*)d_in[17]};
    const float* gw1 = (const float*)d_in[18]; const float* gb1 = (const float*)d_in[19];
    const float* gw2 = (const float*)d_in[20]; const float* gb2 = (const float*)d_in[21];
    const float* gw3 = (const float*)d_in[22]; const float* gb3 = (const float*)d_in[23];
    const float* gw4 = (const float*)d_in[24]; const float* gb4 = (const float*)d_in[25];
    const float* fw1 = (const float*)d_in[26]; const float* fb1 = (const float*)d_in[27];
    const float* fw2 = (const float*)d_in[28]; const float* fb2 = (const float*)d_in[29];
    const float* fw3 = (const float*)d_in[30]; const float* fb3 = (const float*)d_in[31];

    float* ws  = (float*)d_ws;
    float* x1  = ws;                     // 6291456
    float* x2  = x1 + 6291456;           // 1572864
    float* x3  = x2 + 1572864;           // 393216
    float* x4  = x3 + 393216;            // 98304
    float* sums = x4 + 98304;            // 192
    float* U   = sums + 192;             // 1048576
    float* V   = U + 1048576;            // 1048576
    float* wqv = V + 1048576;            // 16384
    float* part = wqv + 16384;           // 262144
    bf16_t* wpack = (bf16_t*)(part + 262144);  // 3*65536 bf16

    prep_kernel<<<64, 256, 0, stream>>>(q, gw1, gb1, gw2, gw3, gw4,
                                        sums, wqv, wpack);
    conv1_kernel<<<256, 256, 0, stream>>>(img, cw[0], cb[0], x1, sums + 0);
    convN_kernel<32, 8, 4><<<256, 256, 0, stream>>>(x1, sums + 0, 262144.f,
        bg[0], bbv[0], cw[1], cb[1], x2, sums + 48);
    convN_kernel<16, 8, 2><<<128, 128, 0, stream>>>(x2, sums + 48, 65536.f,
        bg[1], bbv[1], cw[2], cb[2], x3, sums + 96);
    convN_kernel<8, 8, 1><<<64, 64, 0, stream>>>(x3, sums + 96, 16384.f,
        bg[2], bbv[2], cw[3], cb[3], x4, sums + 144);
    uv_kernel<<<256, 256, 0, stream>>>(x4, sums + 144, bg[3], bbv[3], gw1, U, V);
    pair_kernel<<<1024, 512, 0, stream>>>(U, V, wqv, wpack, gb2, gb3, gb4, part);
    fphi_kernel<<<64, 256, 0, stream>>>(part, fw1, fb1, fw2, fb2, fw3, fb3,
                                        (float*)d_out);
}